// Round 8
// baseline (66.827 us; speedup 1.0000x reference)
//
#include <hip/hip_runtime.h>
#include <stdint.h>

// Radius-graph edge list, B=4, N=2048, cutoff 5.0.
// Output [2, B*P] int32: compacted valid edges (ascending flat index), -1 pad.
//
// Round-13: two dispatches, COMPOSE instead of fill-then-overwrite.
//   K1 count_kernel (2047 blk, kItems=16, validated r5/r6 walk): counts[bid],
//      stash[<=128/blk], and atomicAdd(total, blockCount). ~0.2 MB writes.
//   K2 fill_compose (2047 blk): load T=total (4B, L2-hot). Blocks with
//      base >= T (99.85%: T ~ 12K of 8.4M): pure -1 int4 fill, stores issue
//      immediately, NO barrier after stores, retire. Hot blocks (~3): scan
//      counts -> LDS offs (barrier BEFORE stores), then compose each int4
//      directly as edge-value-or--1 via binary search + stash. Fill and
//      placement are ONE store pass: no W-W race, no ordering needed.
// Measured lessons pinned:
//   r3 coop grid.sync = 286 us (L2 flush / XCDs). r5 nontemporal+fence =
//   233 us (287 GB/s writes). r6 barrier-after-fill = +20 us (vmcnt(0)
//   drain). r1 prefix-before-fill for all blocks = +4 us. r7 scatter
//   early-exit = 0 (scatter already hidden): slack is dispatch structure.

namespace {
constexpr int kB = 4;
constexpr int kN = 2048;
constexpr int kP = kN * (kN - 1) / 2;              // 2096128
constexpr long long kTotal = (long long)kB * kP;   // 8384512
constexpr int kBlock = 256;
constexpr int kItems = 16;
constexpr int kChunk = kBlock * kItems;            // 4096
constexpr int kGrid = (int)(kTotal / kChunk);      // 2047 (exact)
constexpr float kCut2 = 25.0f;                     // 5.0^2
constexpr int kCap = 128;                          // stash slots per block
}  // namespace

// p in [0,P) -> (i,j), i<j, triu row-major. Closed-form sqrt guess + exact
// integer fixup. C(i) = i*(4095-i)/2. disc < 2^24 so float sqrt is tight.
__device__ __forceinline__ void decode_pair(int p, int& i, int& j) {
  float t = sqrtf((float)(16769025 - 8 * p));
  int ii = (int)((4095.0f - t) * 0.5f);
  ii = ii < 0 ? 0 : (ii > kN - 2 ? kN - 2 : ii);
  while (ii > 0 && (ii * (4095 - ii)) / 2 > p) --ii;
  while (ii < kN - 2 && ((ii + 1) * (4094 - ii)) / 2 <= p) ++ii;
  i = ii;
  j = ii + 1 + (p - (ii * (4095 - ii)) / 2);
}

__device__ __forceinline__ bool pair_test(const float* __restrict__ x, int b, int p,
                                          int& gi, int& gj) {
  int i, j;
  decode_pair(p, i, j);
  const float* xb = x + (size_t)b * kN * 3;
  float dx = xb[3 * i + 0] - xb[3 * j + 0];
  float dy = xb[3 * i + 1] - xb[3 * j + 1];
  float dz = xb[3 * i + 2] - xb[3 * j + 2];
  gi = b * kN + i;
  gj = b * kN + j;
  return dx * dx + dy * dy + dz * dz <= kCut2;
}

// ---------------------------------------------------------------------------
// K1: pair tests -> counts + stash + total. No output traffic.
// (r5/r6 phase-A walk, validated absmax 0.)
// ---------------------------------------------------------------------------
__global__ __launch_bounds__(kBlock) void count_kernel(
    const float* __restrict__ x, uint32_t* __restrict__ counts,
    uint32_t* __restrict__ total, int2* __restrict__ stash) {
  const int t = threadIdx.x;
  const int wave = t >> 6, lane = t & 63;
  const int bid = blockIdx.x;
  const int base = bid * kChunk;

  __shared__ uint32_t slot[kItems * 4];  // 64 (item,wave) counts / scan

  if (bid == 0 && t == 0) counts[kGrid] = 0;  // pad -> 2048 uint4-loadable

  // One sqrt-decode per thread, then incremental row-walk (+256/item).
  int b = base / kP;
  int p = base - b * kP + t;
  if (p >= kP) { p -= kP; ++b; }
  int i, j;
  decode_pair(p, i, j);
  int ib = b * kN;

  const float3* __restrict__ x3 = (const float3*)x;
  float3 pi = x3[ib + i];

  uint32_t hits = 0;  // bit k = item k is an edge
#pragma unroll
  for (int k = 0; k < kItems; ++k) {
    float3 pj = x3[ib + j];
    float dx = pi.x - pj.x, dy = pi.y - pj.y, dz = pi.z - pj.z;
    if (dx * dx + dy * dy + dz * dz <= kCut2) hits |= (1u << k);
    if (k < kItems - 1) {
      j += kBlock;
      if (j >= kN) {  // row advance, mostly wave-coherent
        do {
          int ex = j - kN;
          ++i;
          if (i >= kN - 1) { i = 0; ib += kN; }
          j = i + 1 + ex;
        } while (j >= kN);
        pi = x3[ib + i];
      }
    }
  }

  if (t < kItems * 4) slot[t] = 0;
  __syncthreads();

  const bool waveany = (__ballot(hits != 0) != 0ULL);  // wave-uniform
  if (waveany) {
#pragma unroll
    for (int k = 0; k < kItems; ++k) {
      unsigned long long m = __ballot((hits >> k) & 1u);
      if (m != 0ULL && lane == 0) slot[k * 4 + wave] = (uint32_t)__popcll(m);
    }
  }
  __syncthreads();
  if (t < 64) {  // exclusive scan of 64 (item,wave) counts in one wave
    uint32_t v = slot[t];
    uint32_t run = v;
    for (int o = 1; o < 64; o <<= 1) {
      uint32_t u = __shfl_up(run, o, 64);
      if (lane >= o) run += u;
    }
    slot[t] = run - v;
    if (t == 63) {
      counts[bid] = run;          // block total
      if (run) atomicAdd(total, run);
    }
  }
  __syncthreads();
  if (waveany) {
#pragma unroll
    for (int k = 0; k < kItems; ++k) {
      bool f = (hits >> k) & 1u;
      unsigned long long m = __ballot(f);
      if (m != 0ULL && f) {  // rare: ~6 hits per block expected
        int pf = base + k * kBlock + t;
        int hb = pf / kP;
        int hp = pf - hb * kP;
        int hi, hj;
        decode_pair(hp, hi, hj);
        uint32_t pos = slot[k * 4 + wave] +
                       (uint32_t)__popcll(m & ((1ULL << lane) - 1ULL));
        if (pos < (uint32_t)kCap)
          stash[(size_t)bid * kCap + pos] = make_int2(hb * kN + hi, hb * kN + hj);
      }
    }
  }
}

// ---------------------------------------------------------------------------
// K2: compose-and-store. Cold blocks (base >= T): pure -1 fill, no reads
// beyond T, no barriers. Hot blocks (~3): scan counts (barrier BEFORE the
// stores), then one composed store pass. No W-W races anywhere.
// ---------------------------------------------------------------------------
__global__ __launch_bounds__(kBlock) void fill_compose_kernel(
    const float* __restrict__ x, const uint32_t* __restrict__ counts,
    const uint32_t* __restrict__ total, const int2* __restrict__ stash,
    int* __restrict__ out) {
  const int t = threadIdx.x;
  const int wave = t >> 6, lane = t & 63;
  const int bid = blockIdx.x;
  const int base = bid * kChunk;  // int position within each row

  const uint32_t T = *total;

  int4* o0 = (int4*)out + (base >> 2);
  int4* o1 = (int4*)(out + kTotal) + (base >> 2);

  if ((uint32_t)base >= T) {  // cold path: 99.85% of blocks
    const int4 m1 = make_int4(-1, -1, -1, -1);
#pragma unroll
    for (int s = 0; s < 4; ++s) {
      o0[t + s * kBlock] = m1;
      o1[t + s * kBlock] = m1;
    }
    return;
  }

  // Hot path: scan all 2048 counts into LDS offs (r5 finisher scan,
  // validated). Barrier is BEFORE the big stores -> no vmcnt-drain trap.
  __shared__ uint32_t offs[kGrid + 1];  // 8 KB
  __shared__ uint32_t wred[4];
  uint32_t c[8];
  {
    const uint4* c4 = (const uint4*)counts;
    uint4 a = c4[t * 2 + 0];
    uint4 bb = c4[t * 2 + 1];
    c[0] = a.x; c[1] = a.y; c[2] = a.z; c[3] = a.w;
    c[4] = bb.x; c[5] = bb.y; c[6] = bb.z; c[7] = bb.w;
  }
  uint32_t tsum = 0;
#pragma unroll
  for (int q = 0; q < 8; ++q) tsum += c[q];
  uint32_t run = tsum;  // wave-inclusive scan of per-thread sums
  for (int o = 1; o < 64; o <<= 1) {
    uint32_t u = __shfl_up(run, o, 64);
    if (lane >= o) run += u;
  }
  if (lane == 63) wred[wave] = run;
  __syncthreads();
  uint32_t wbase = 0;
  for (int w = 0; w < 4; ++w)
    if (w < wave) wbase += wred[w];
  uint32_t excl = wbase + run - tsum;
#pragma unroll
  for (int q = 0; q < 8; ++q) {
    offs[t * 8 + q] = excl;
    excl += c[q];
  }
  __syncthreads();

  // Compose: one store pass, each int4 holds edge values (< T) or -1 (>= T).
#pragma unroll
  for (int s = 0; s < 4; ++s) {
    int4 v0, v1;
    int* p0 = &v0.x;
    int* p1 = &v1.x;
#pragma unroll
    for (int cc = 0; cc < 4; ++cc) {
      uint32_t e = (uint32_t)base + (uint32_t)((t + s * kBlock) << 2) + cc;
      int g0 = -1, g1 = -1;
      if (e < T) {
        int lo = 0, hi = kGrid - 1;  // largest lo with offs[lo] <= e
        while (lo < hi) {
          int mid = (lo + hi + 1) >> 1;
          if (offs[mid] <= e) lo = mid; else hi = mid - 1;
        }
        uint32_t idx = e - offs[lo];
        if (idx < (uint32_t)kCap) {
          int2 vv = stash[(size_t)lo * kCap + idx];
          g0 = vv.x;
          g1 = vv.y;
        } else {
          // Never-path (owning block count > kCap): serial re-walk for the
          // idx-th hit of block lo. Exact.
          uint32_t seen = 0;
          const int obase = lo * kChunk;
          for (int q = 0; q < kChunk; ++q) {
            int pf = obase + q;
            int hb = pf / kP, hp = pf - hb * kP;
            int gi_, gj_;
            if (pair_test(x, hb, hp, gi_, gj_)) {
              if (seen == idx) { g0 = gi_; g1 = gj_; break; }
              ++seen;
            }
          }
        }
      }
      p0[cc] = g0;
      p1[cc] = g1;
    }
    o0[t + s * kBlock] = v0;
    o1[t + s * kBlock] = v1;
  }
}

extern "C" void kernel_launch(void* const* d_in, const int* in_sizes, int n_in,
                              void* d_out, int out_size, void* d_ws, size_t ws_size,
                              hipStream_t stream) {
  const float* x = (const float*)d_in[0];
  int* out = (int*)d_out;
  uint32_t* counts = (uint32_t*)d_ws;           // [2048] (idx 2047 = pad)
  uint32_t* total = counts + 2048;              // [1]
  int2* stash = (int2*)(counts + 2056);         // [2047 * kCap] ~2.1 MB

  (void)hipMemsetAsync(total, 0, sizeof(uint32_t), stream);  // graph-capturable
  hipLaunchKernelGGL(count_kernel, dim3(kGrid), dim3(kBlock), 0, stream, x, counts,
                     total, stash);
  hipLaunchKernelGGL(fill_compose_kernel, dim3(kGrid), dim3(kBlock), 0, stream, x,
                     counts, total, stash, out);
}

// Round 9
// 61.203 us; speedup vs baseline: 1.0919x; 1.0919x over previous
//
#include <hip/hip_runtime.h>
#include <stdint.h>

// Radius-graph edge list, B=4, N=2048, cutoff 5.0.
// Output [2, B*P] int32: compacted valid edges (ascending flat index), -1 pad.
//
// Round-14: r7 kernel (32.46 us, best) with ONE change: the pass1 hot loop
// does per-item CLOSED-FORM decode instead of the incremental row-walk.
//   Evidence (r8): count-only kernel with the incremental walk = 42.7 us
//   (kItems=16) -> the walk is a serial per-thread dependency chain with a
//   divergent multi-row do-while (100+ masked iters/jump in each batch's
//   short-row tail); it, not the 67 MB fill (11 us floor), dominates pass1.
//   Independent items = loads pipelined by the compiler, no tail pathology,
//   lanes adjacent in p so loads stay coalesced.
// Measured lessons pinned:
//   r3 coop grid.sync = 286 us (L2 flush / XCDs). r5 nontemporal+fence =
//   233 us (287 GB/s writes). r6 barrier-after-fill = vmcnt(0) drain trap.
//   r8 same-address atomicAdd from 2047 blocks ~ +10 us. r7 scatter
//   early-exit = free (kept). r1/r2: cross-kernel fill/prefix moves lose.

namespace {
constexpr int kB = 4;
constexpr int kN = 2048;
constexpr int kP = kN * (kN - 1) / 2;              // 2096128
constexpr long long kTotal = (long long)kB * kP;   // 8384512
constexpr int kBlock = 256;
constexpr int kItems = 8;
constexpr int kChunk = kBlock * kItems;            // 2048
constexpr int kNBlk = (int)(kTotal / kChunk);      // 4094 (exact, no tail)
constexpr float kCut2 = 25.0f;                     // 5.0^2
constexpr int kCap = 128;                          // stash slots per block
}  // namespace

// p in [0,P) -> (i,j), i<j, triu row-major. Closed-form sqrt guess + exact
// integer fixup. C(i) = i*(4095-i)/2; products < 2^24 so __mul24 is exact
// and the float sqrt guess is within +-1 (fixup whiles run 0-1 iters).
__device__ __forceinline__ void decode_pair(int p, int& i, int& j) {
  float t = sqrtf((float)(16769025 - 8 * p));
  int ii = (int)((4095.0f - t) * 0.5f);
  ii = ii < 0 ? 0 : (ii > kN - 2 ? kN - 2 : ii);
  while (ii > 0 && (__mul24(ii, 4095 - ii) >> 1) > p) --ii;
  while (ii < kN - 2 && (__mul24(ii + 1, 4094 - ii) >> 1) <= p) ++ii;
  i = ii;
  j = ii + 1 + (p - (__mul24(ii, 4095 - ii) >> 1));
}

__device__ __forceinline__ bool pair_test(const float* __restrict__ x, int b, int p,
                                          int& gi, int& gj) {
  int i, j;
  decode_pair(p, i, j);
  const float* xb = x + (size_t)b * kN * 3;
  float dx = xb[3 * i + 0] - xb[3 * j + 0];
  float dy = xb[3 * i + 1] - xb[3 * j + 1];
  float dz = xb[3 * i + 2] - xb[3 * j + 2];
  gi = b * kN + i;
  gj = b * kN + j;
  return dx * dx + dy * dy + dz * dz <= kCut2;
}

__global__ __launch_bounds__(kBlock) void pass1_kernel(const float* __restrict__ x,
                                                       uint32_t* __restrict__ counts,
                                                       int2* __restrict__ stash,
                                                       int* __restrict__ out) {
  const int t = threadIdx.x;
  const int wave = t >> 6, lane = t & 63;
  const int bid = blockIdx.x;
  const int base = bid * kChunk;

  // Fill this block's slice of both output rows with -1 (2048 ints each).
  // Zero-dependency stores: issue from cycle 0, drain under the compute.
  {
    const int4 m1 = make_int4(-1, -1, -1, -1);
    int4* o0 = (int4*)out + (base >> 2);
    int4* o1 = (int4*)(out + kTotal) + (base >> 2);
    o0[t] = m1;
    o0[t + kBlock] = m1;
    o1[t] = m1;
    o1[t + kBlock] = m1;
  }
  if (bid == 0 && t < 2) counts[kNBlk + t] = 0;  // pad so scatter can uint4-load

  // Per-item closed-form decode: 8 INDEPENDENT pair tests per thread (no
  // serial walk chain, no divergent multi-row advance). A block spans at
  // most one batch boundary; resolve b with one compare per item.
  const int b0 = base / kP;
  const int rel0 = base - b0 * kP + t;  // relative p of item 0 (may exceed kP)
  const float3* __restrict__ x3 = (const float3*)x;

  uint32_t hits = 0;  // bit k = item k is an edge
#pragma unroll
  for (int k = 0; k < kItems; ++k) {
    int rel = rel0 + k * kBlock;
    int b = b0;
    if (rel >= kP) { rel -= kP; ++b; }
    int i, j;
    decode_pair(rel, i, j);
    const int ib = b * kN;
    float3 pi = x3[ib + i];
    float3 pj = x3[ib + j];
    float dx = pi.x - pj.x, dy = pi.y - pj.y, dz = pi.z - pj.z;
    if (dx * dx + dy * dy + dz * dz <= kCut2) hits |= (1u << k);
  }

  __shared__ uint32_t slot[32];
  if (t < 32) slot[t] = 0;
  __syncthreads();

  const bool waveany = (__ballot(hits != 0) != 0ULL);  // wave-uniform
  if (waveany) {
#pragma unroll
    for (int k = 0; k < kItems; ++k) {
      unsigned long long m = __ballot((hits >> k) & 1u);
      if (m != 0ULL && lane == 0) slot[k * 4 + wave] = (uint32_t)__popcll(m);
    }
  }
  __syncthreads();
  if (t < 32) {  // exclusive scan of 32 (item,wave) counts; write block total
    uint32_t v = slot[t];
    uint32_t run = v;
    for (int off = 1; off < 32; off <<= 1) {
      uint32_t u = __shfl_up(run, off, 64);
      if (t >= off) run += u;
    }
    slot[t] = run - v;
    if (t == 31) counts[bid] = run;
  }
  __syncthreads();
  if (waveany) {
#pragma unroll
    for (int k = 0; k < kItems; ++k) {
      bool f = (hits >> k) & 1u;
      unsigned long long m = __ballot(f);
      if (m != 0ULL && f) {  // rare: ~3 hits per block total
        int pf = base + k * kBlock + t;
        int hb = pf / kP;
        int hp = pf - hb * kP;
        int hi, hj;
        decode_pair(hp, hi, hj);
        uint32_t pos = slot[k * 4 + wave] +
                       (uint32_t)__popcll(m & ((1ULL << lane) - 1ULL));
        if (pos < (uint32_t)kCap)
          stash[(size_t)bid * kCap + pos] = make_int2(hb * kN + hi, hb * kN + hj);
      }
    }
  }
}

__global__ __launch_bounds__(kBlock) void scatter_kernel(const float* __restrict__ x,
                                                         const uint32_t* __restrict__ counts,
                                                         const int2* __restrict__ stash,
                                                         int* __restrict__ out) {
  const int bid = blockIdx.x;
  const int t = threadIdx.x;

  // Own count first; ~4091/4094 blocks exit on one broadcast load. (r7)
  const uint32_t cnt = counts[bid];
  if (cnt == 0) return;

  // Self-service prefix: offset = sum(counts[idx < bid]), from 16 KB L2-hot.
  const uint4* c4 = (const uint4*)counts;  // [4096] incl. zero pad
  uint32_t part = 0;
#pragma unroll
  for (int q = 0; q < 4; ++q) {
    uint4 v = c4[t * 4 + q];
    int i0 = t * 16 + q * 4;
    part += (i0 + 0 < bid) ? v.x : 0u;
    part += (i0 + 1 < bid) ? v.y : 0u;
    part += (i0 + 2 < bid) ? v.z : 0u;
    part += (i0 + 3 < bid) ? v.w : 0u;
  }
  for (int o = 32; o > 0; o >>= 1) part += __shfl_down(part, o, 64);
  __shared__ uint32_t wred[4];
  if ((t & 63) == 0) wred[t >> 6] = part;
  __syncthreads();
  if (t == 0) wred[0] = wred[0] + wred[1] + wred[2] + wred[3];
  __syncthreads();
  const uint32_t off = wred[0];

  if (cnt <= (uint32_t)kCap) {
    for (uint32_t e = t; e < cnt; e += kBlock) {
      int2 v = stash[(size_t)bid * kCap + e];
      out[off + e] = v.x;
      out[(size_t)kTotal + off + e] = v.y;
    }
    return;
  }
  // Overflow fallback (count > kCap): recompute this block's edges with
  // ballot ranks and write directly. Deterministic + exact.
  const int wave = t >> 6, lane = t & 63;
  const int base = bid * kChunk;
  const int bb0 = base / kP;
  const int p0 = base - bb0 * kP;
  __shared__ uint32_t slot[kItems * 4];
  unsigned long long masks[kItems];
  int gi[kItems], gj[kItems];
  bool fl[kItems];
  for (int k = 0; k < kItems; ++k) {
    int o = k * kBlock + t;
    int b = bb0, p = p0 + o;
    if (p >= kP) { p -= kP; ++b; }
    fl[k] = pair_test(x, b, p, gi[k], gj[k]);
    masks[k] = __ballot(fl[k]);
    if (lane == 0) slot[k * 4 + wave] = (uint32_t)__popcll(masks[k]);
  }
  __syncthreads();
  if (t == 0) {
    uint32_t run = 0;
    for (int s = 0; s < kItems * 4; ++s) {
      uint32_t c = slot[s];
      slot[s] = run;
      run += c;
    }
  }
  __syncthreads();
  for (int k = 0; k < kItems; ++k) {
    if (fl[k]) {
      uint32_t pos = off + slot[k * 4 + wave] +
                     (uint32_t)__popcll(masks[k] & ((1ULL << lane) - 1ULL));
      out[pos] = gi[k];
      out[(size_t)kTotal + pos] = gj[k];
    }
  }
}

extern "C" void kernel_launch(void* const* d_in, const int* in_sizes, int n_in,
                              void* d_out, int out_size, void* d_ws, size_t ws_size,
                              hipStream_t stream) {
  const float* x = (const float*)d_in[0];
  int* out = (int*)d_out;
  uint32_t* counts = (uint32_t*)d_ws;                 // [4096] (2 pad)
  int2* stash = (int2*)(counts + 4096);               // [4094 * kCap] ~4.2 MB

  hipLaunchKernelGGL(pass1_kernel, dim3(kNBlk), dim3(kBlock), 0, stream, x, counts,
                     stash, out);
  hipLaunchKernelGGL(scatter_kernel, dim3(kNBlk), dim3(kBlock), 0, stream, x, counts,
                     stash, out);
}